// Round 1
// baseline (680.214 us; speedup 1.0000x reference)
//
#include <hip/hip_runtime.h>
#include <stdint.h>

#define NMASK 16
#define HW_P 589824            // 768*768 pixels per mask
#define WORDS_PER_MASK 18432   // HW_P / 32
#define CHUNKS_PER_MASK 4608   // WORDS_PER_MASK / 4 (uint4 chunks)
#define SEQ_THREADS 512
#define VPT 9                  // uint4 chunks per thread per mask: 4608/512

// ---------------- kernel 1: binarize masks into bitsets + popcounts --------
// 1152 blocks x 256 threads; blocks 0..575 -> tensor A, 576..1151 -> tensor B.
// Each block covers 16384 consecutive elements (36 blocks per mask, exact).
__global__ __launch_bounds__(256) void binarize_kernel(
    const float* __restrict__ ma, const float* __restrict__ mb,
    uint32_t* __restrict__ bitsA, uint32_t* __restrict__ bitsB,
    int* __restrict__ pcA, int* __restrict__ pcB)
{
    const int ELEMS = 16384;
    int blk = blockIdx.x;
    int tensor = (blk >= 576);
    int rel = tensor ? (blk - 576) : blk;
    const float* src = tensor ? mb : ma;
    uint32_t* bits = tensor ? bitsB : bitsA;
    int* pc = tensor ? pcB : pcA;
    int base = rel * ELEMS;
    int m = base / HW_P;              // block entirely inside one mask
    int lane = threadIdx.x & 63;
    int cnt = 0;
    for (int it = 0; it < 64; ++it) {
        int e = base + it * 256 + (int)threadIdx.x;
        float v = src[e];
        unsigned long long mk = __ballot(v > 0.0f);   // bit l = lane l pred
        int e0 = e & ~63;                              // wave-chunk base elem
        if (lane == 0) {
            bits[e0 >> 5] = (uint32_t)mk;
            cnt += __popcll(mk);
        } else if (lane == 1) {
            bits[(e0 >> 5) + 1] = (uint32_t)(mk >> 32);
        }
    }
    if (lane == 0) atomicAdd(&pc[m], cnt);
}

// ---------------- kernel 2: the sequential 256-pair filter -----------------
// Single workgroup (1 CU): bitsets stay coherent through this CU's L1/L2.
// Thread t owns uint4 chunks {t + 512*w} of every mask -> fixed partition, so
// all global RAW hazards are same-thread same-address (plus __syncthreads
// drains vmcnt every pair). A[i] lives in registers across the j loop;
// B[j+1] and A[i+1] are prefetched (provably untouched by current pair).
__global__ __launch_bounds__(SEQ_THREADS, 2) void seq_filter_kernel(
    const float* __restrict__ sa_g, const float* __restrict__ sb_g,
    uint32_t* bitsA, uint32_t* bitsB,
    const int* __restrict__ pcA_g, const int* __restrict__ pcB_g,
    int* flagsA, int* flagsB)
{
    const int tid = threadIdx.x;
    const int wave = tid >> 6;
    const int lane = tid & 63;
    __shared__ float sA[NMASK], sB[NMASK];
    __shared__ int partial[2][SEQ_THREADS / 64];   // double-buffered by pair parity

    if (tid < NMASK) sA[tid] = sa_g[tid];
    else if (tid < 2 * NMASK) sB[tid - NMASK] = sb_g[tid - NMASK];

    // Per-thread (uniform) copies of popcounts -> no LDS read/write races.
    int pca[NMASK], pcb[NMASK];
#pragma unroll
    for (int m = 0; m < NMASK; ++m) { pca[m] = pcA_g[m]; pcb[m] = pcB_g[m]; }

    unsigned fA = 0u, fB = 0u;   // suppression flags, maintained uniformly
    uint4 a[VPT], b[VPT], bn[VPT], an[VPT];
    uint4* A4 = (uint4*)bitsA;
    uint4* B4 = (uint4*)bitsB;

#pragma unroll
    for (int w = 0; w < VPT; ++w) a[w]  = A4[tid + SEQ_THREADS * w];
#pragma unroll
    for (int w = 0; w < VPT; ++w) bn[w] = B4[tid + SEQ_THREADS * w];
    __syncthreads();

    int par = 0;
    for (int i = 0; i < NMASK; ++i) {
        if (i < NMASK - 1) {   // A[i+1] immutable during row i -> safe prefetch
#pragma unroll
            for (int w = 0; w < VPT; ++w)
                an[w] = A4[(i + 1) * CHUNKS_PER_MASK + tid + SEQ_THREADS * w];
        }
        for (int j = 0; j < NMASK; ++j) {
#pragma unroll
            for (int w = 0; w < VPT; ++w) b[w] = bn[w];
            // prefetch next pair's B (j+1, or B[0] for next row). B[next] is
            // not modified by the current pair -> safe.
            int nj = (j < NMASK - 1) ? (j + 1) : 0;
            if (!(i == NMASK - 1 && j == NMASK - 1)) {
#pragma unroll
                for (int w = 0; w < VPT; ++w)
                    bn[w] = B4[nj * CHUNKS_PER_MASK + tid + SEQ_THREADS * w];
            }
            // intersection popcount over this thread's 36 words
            int s = 0;
#pragma unroll
            for (int w = 0; w < VPT; ++w) {
                s += __popc(a[w].x & b[w].x);
                s += __popc(a[w].y & b[w].y);
                s += __popc(a[w].z & b[w].z);
                s += __popc(a[w].w & b[w].w);
            }
#pragma unroll
            for (int off = 32; off >= 1; off >>= 1) s += __shfl_xor(s, off);
            if (lane == 0) partial[par][wave] = s;
            __syncthreads();
            int inter = 0;
#pragma unroll
            for (int w = 0; w < SEQ_THREADS / 64; ++w) inter += partial[par][w];
            par ^= 1;

            int uni = pca[i] + pcb[j] - inter;
            // replicate reference fp32 arithmetic exactly
            float iou = (float)inter / fmaxf((float)uni, 1.0f);
            bool a_wins = sA[i] > sB[j];
            bool sup = iou > 0.8f;
            if (sup) {
                if (a_wins) fB |= (1u << j); else fA |= (1u << i);
            } else if (inter > 0) {
                if (a_wins) {          // b loses: b &= ~a, store back
                    pcb[j] -= inter;
#pragma unroll
                    for (int w = 0; w < VPT; ++w) {
                        b[w].x &= ~a[w].x; b[w].y &= ~a[w].y;
                        b[w].z &= ~a[w].z; b[w].w &= ~a[w].w;
                    }
                    uint4* dst = B4 + j * CHUNKS_PER_MASK + tid;
#pragma unroll
                    for (int w = 0; w < VPT; ++w) dst[SEQ_THREADS * w] = b[w];
                } else {               // a loses: a &= ~b, stays in registers
                    pca[i] -= inter;
#pragma unroll
                    for (int w = 0; w < VPT; ++w) {
                        a[w].x &= ~b[w].x; a[w].y &= ~b[w].y;
                        a[w].z &= ~b[w].z; a[w].w &= ~b[w].w;
                    }
                }
            }
        }
        // write back final A[i]; advance to prefetched A[i+1]
        uint4* dstA = A4 + i * CHUNKS_PER_MASK + tid;
#pragma unroll
        for (int w = 0; w < VPT; ++w) dstA[SEQ_THREADS * w] = a[w];
        if (i < NMASK - 1) {
#pragma unroll
            for (int w = 0; w < VPT; ++w) a[w] = an[w];
        }
    }
    if (tid < NMASK) flagsA[tid] = (int)((fA >> tid) & 1u);
    else if (tid < 2 * NMASK) flagsB[tid - NMASK] = (int)((fB >> (tid - NMASK)) & 1u);
}

// ---------------- kernel 3: expand bitsets (+keep) to float outputs --------
__global__ __launch_bounds__(256) void expand_kernel(
    const float* __restrict__ ma, const float* __restrict__ mb,
    const uint32_t* __restrict__ bitsA, const uint32_t* __restrict__ bitsB,
    const int* __restrict__ flagsA, const int* __restrict__ flagsB,
    float* __restrict__ out)
{
    int gid = blockIdx.x * 256 + threadIdx.x;   // one float4 per thread
    int e = gid << 2;
    int tensor = (e >= NMASK * HW_P);
    int le = tensor ? (e - NMASK * HW_P) : e;
    int m = le / HW_P;
    const uint32_t* bits = tensor ? bitsB : bitsA;
    const float* src = tensor ? mb : ma;
    const int* flags = tensor ? flagsB : flagsA;
    bool keep = (flags[m] == 0);
    uint32_t wbits = bits[le >> 5];
    int sh = le & 31;
    float4 v = ((const float4*)src)[le >> 2];
    float4 o;
    o.x = (keep && ((wbits >> (sh + 0)) & 1u)) ? v.x : 0.0f;
    o.y = (keep && ((wbits >> (sh + 1)) & 1u)) ? v.y : 0.0f;
    o.z = (keep && ((wbits >> (sh + 2)) & 1u)) ? v.z : 0.0f;
    o.w = (keep && ((wbits >> (sh + 3)) & 1u)) ? v.w : 0.0f;
    ((float4*)out)[gid] = o;
    if (gid < 2 * NMASK) {   // keep_a / keep_b tail as 0/1 floats
        int f = (gid < NMASK) ? flagsA[gid] : flagsB[gid - NMASK];
        out[2 * NMASK * HW_P + gid] = f ? 0.0f : 1.0f;
    }
}

extern "C" void kernel_launch(void* const* d_in, const int* in_sizes, int n_in,
                              void* d_out, int out_size, void* d_ws, size_t ws_size,
                              hipStream_t stream)
{
    const float* ma = (const float*)d_in[0];
    const float* mb = (const float*)d_in[1];
    const float* sa = (const float*)d_in[2];
    const float* sb = (const float*)d_in[3];
    float* out = (float*)d_out;
    char* ws = (char*)d_ws;

    uint32_t* bitsA = (uint32_t*)(ws);                 // 1,179,648 B
    uint32_t* bitsB = (uint32_t*)(ws + 1179648);       // 1,179,648 B
    int* pcA    = (int*)(ws + 2359296);                // 64 B
    int* pcB    = (int*)(ws + 2359360);                // 64 B
    int* flagsA = (int*)(ws + 2359424);                // 64 B
    int* flagsB = (int*)(ws + 2359488);                // 64 B

    hipMemsetAsync(pcA, 0, 128, stream);               // zero pcA + pcB

    binarize_kernel<<<1152, 256, 0, stream>>>(ma, mb, bitsA, bitsB, pcA, pcB);
    seq_filter_kernel<<<1, SEQ_THREADS, 0, stream>>>(sa, sb, bitsA, bitsB,
                                                     pcA, pcB, flagsA, flagsB);
    expand_kernel<<<18432, 256, 0, stream>>>(ma, mb, bitsA, bitsB,
                                             flagsA, flagsB, out);
}

// Round 2
// 350.115 us; speedup vs baseline: 1.9428x; 1.9428x over previous
//
#include <hip/hip_runtime.h>
#include <stdint.h>

#define NM 16
#define HW_P 589824            // 768*768 pixels per mask
#define WPM 18432              // 32-bit words per mask
#define CPM 4608               // uint4 chunks per mask
#define WPT 294912             // words per tensor (16 masks)
#define SLOT_U4 4612           // uint4 stride per message slot (4608 data + meta pad)
#define PT 512                 // pipeline kernel threads

// meta int layout in workspace:
// [0..15] pcA | [16..31] pcB | [32..47] flagsA | [48..63] flagsB
// [64..79] prod counters (boundary j -> j+1) | [80..95] cons counters

// ---------------- kernel 1: binarize masks into bitsets + popcounts --------
// One thread per 32-bit word: 8 float4 loads (128 B contiguous), 1 dword store.
__global__ __launch_bounds__(256) void binarize_kernel(
    const float* __restrict__ ma, const float* __restrict__ mb,
    uint32_t* __restrict__ bitsA, uint32_t* __restrict__ bitsB,
    int* __restrict__ meta)
{
    int w = blockIdx.x * 256 + threadIdx.x;      // global word 0..589823
    int tensor = (w >= WPT);
    int lw = tensor ? (w - WPT) : w;
    const float* src = tensor ? mb : ma;
    uint32_t* bits = tensor ? bitsB : bitsA;
    int* pc = meta + (tensor ? 16 : 0);
    int m = lw / WPM;                            // compiler magic-muls
    const float4* s4 = (const float4*)(src + (size_t)lw * 32);
    uint32_t wd = 0;
#pragma unroll
    for (int q = 0; q < 8; ++q) {
        float4 v = s4[q];
        wd |= (v.x > 0.0f ? 1u : 0u) << (q * 4 + 0);
        wd |= (v.y > 0.0f ? 1u : 0u) << (q * 4 + 1);
        wd |= (v.z > 0.0f ? 1u : 0u) << (q * 4 + 2);
        wd |= (v.w > 0.0f ? 1u : 0u) << (q * 4 + 3);
    }
    bits[lw] = wd;
    int s = __popc(wd);
#pragma unroll
    for (int off = 32; off >= 1; off >>= 1) s += __shfl_xor(s, off);
    // 18432 % 64 == 0 and 294912 % 64 == 0 -> a wave never straddles masks
    if ((threadIdx.x & 63) == 0) atomicAdd(&pc[m], s);
}

// ---------------- kernel 2: systolic wavefront pipeline --------------------
// WG j owns column j: b_j lives in registers for the whole kernel. a_i flows
// j-1 -> j as a 72 KB message (double-buffered slots, credit-based reuse).
// Producer: data stores -> __syncthreads (vmcnt drain into L2) -> agent
// RELEASE flag store (buffer_wbl2). Consumer: agent ACQUIRE poll (buffer_inv)
// -> __syncthreads -> vector loads. 31 diagonal stages total.
__global__ __launch_bounds__(PT) void pipeline_kernel(
    const float* __restrict__ sa, const float* __restrict__ sb,
    uint32_t* bitsA, uint32_t* bitsB, int* meta, uint4* msg)
{
    int* pcA    = meta;
    int* pcB    = meta + 16;
    int* flagsA = meta + 32;
    int* flagsB = meta + 48;
    int* prod   = meta + 64;
    int* cons   = meta + 80;

    const int j = blockIdx.x;
    const int tid = threadIdx.x;
    const int wave = tid >> 6, lane = tid & 63;

    __shared__ int partial[2][PT / 64];
    __shared__ int smeta[2];

    uint4* A4 = (uint4*)bitsA;
    uint4* B4 = (uint4*)bitsB;

    uint4 a[9], b[9];
#pragma unroll
    for (int w = 0; w < 9; ++w) b[w] = B4[(size_t)j * CPM + tid + PT * w];
    int pcb = pcB[j];
    float sbj = sb[j];
    int fBj = 0;
    int par = 0;

    for (int i = 0; i < NM; ++i) {
        uint4* slot_in  = (j > 0) ? (msg + (size_t)((j - 1) * 2 + (i & 1)) * SLOT_U4) : msg;
        uint4* slot_out = msg + (size_t)(j * 2 + (i & 1)) * SLOT_U4;

        if (j > 0 && tid == 0) {
            while (__hip_atomic_load(&prod[j - 1], __ATOMIC_ACQUIRE,
                                     __HIP_MEMORY_SCOPE_AGENT) < i + 1)
                __builtin_amdgcn_s_sleep(1);
            int* mi = (int*)(slot_in + CPM);
            smeta[0] = __hip_atomic_load(mi + 0, __ATOMIC_RELAXED, __HIP_MEMORY_SCOPE_AGENT);
            smeta[1] = __hip_atomic_load(mi + 1, __ATOMIC_RELAXED, __HIP_MEMORY_SCOPE_AGENT);
        }
        if (j < NM - 1 && i >= 2 && tid == 1) {
            while (__hip_atomic_load(&cons[j], __ATOMIC_RELAXED,
                                     __HIP_MEMORY_SCOPE_AGENT) < i - 1)
                __builtin_amdgcn_s_sleep(1);
        }
        __syncthreads();   // B1: flag seen + caches invalidated (tid0 wave) for all

        int pca, fAi;
        const uint4* srcA = (j == 0) ? (A4 + (size_t)i * CPM) : slot_in;
#pragma unroll
        for (int w = 0; w < 9; ++w) a[w] = srcA[tid + PT * w];
        if (j == 0) { pca = pcA[i]; fAi = 0; }
        else        { pca = smeta[0]; fAi = smeta[1]; }

        int s = 0;
#pragma unroll
        for (int w = 0; w < 9; ++w) {
            s += __popc(a[w].x & b[w].x);
            s += __popc(a[w].y & b[w].y);
            s += __popc(a[w].z & b[w].z);
            s += __popc(a[w].w & b[w].w);
        }
#pragma unroll
        for (int off = 32; off >= 1; off >>= 1) s += __shfl_xor(s, off);
        if (lane == 0) partial[par][wave] = s;
        __syncthreads();   // B2: partials visible AND all message loads retired

        if (j > 0 && tid == 0)   // slot consumed -> release credit
            __hip_atomic_store(&cons[j - 1], i + 1, __ATOMIC_RELAXED,
                               __HIP_MEMORY_SCOPE_AGENT);

        int inter = 0;
#pragma unroll
        for (int w = 0; w < PT / 64; ++w) inter += partial[par][w];
        par ^= 1;

        // replicate reference fp32 arithmetic exactly
        int uni = pca + pcb - inter;
        float iou = (float)inter / fmaxf((float)uni, 1.0f);
        bool a_wins = sa[i] > sbj;
        if (iou > 0.8f) {
            if (a_wins) fBj = 1; else fAi = 1;
        } else if (inter > 0) {
            if (a_wins) {          // b loses: b &= ~a (stays in registers)
                pcb -= inter;
#pragma unroll
                for (int w = 0; w < 9; ++w) {
                    b[w].x &= ~a[w].x; b[w].y &= ~a[w].y;
                    b[w].z &= ~a[w].z; b[w].w &= ~a[w].w;
                }
            } else {               // a loses: a &= ~b (message updated)
                pca -= inter;
#pragma unroll
                for (int w = 0; w < 9; ++w) {
                    a[w].x &= ~b[w].x; a[w].y &= ~b[w].y;
                    a[w].z &= ~b[w].z; a[w].w &= ~b[w].w;
                }
            }
        }

        if (j < NM - 1) {
#pragma unroll
            for (int w = 0; w < 9; ++w) slot_out[tid + PT * w] = a[w];
            __syncthreads();   // B3: all data stores acked into L2
            if (tid == 0) {
                int* mo = (int*)(slot_out + CPM);
                mo[0] = pca; mo[1] = fAi;
                // RELEASE: waitcnt + buffer_wbl2 flushes all dirty L2 (incl.
                // every thread's slot stores) to the coherent point, then flag.
                __hip_atomic_store(&prod[j], i + 1, __ATOMIC_RELEASE,
                                   __HIP_MEMORY_SCOPE_AGENT);
            }
        } else {
            // last column: a_i is final. WG0 read original row i long ago
            // (happens-before via the message chain), so overwrite in place.
            uint4* dst = A4 + (size_t)i * CPM;
#pragma unroll
            for (int w = 0; w < 9; ++w) dst[tid + PT * w] = a[w];
            if (tid == 0) flagsA[i] = fAi;
        }
    }
    // final b_j (column-owned) back to bitsB; end-of-kernel flush makes it
    // visible to expand_kernel.
#pragma unroll
    for (int w = 0; w < 9; ++w) B4[(size_t)j * CPM + tid + PT * w] = b[w];
    if (tid == 0) flagsB[j] = fBj;
}

// ---------------- kernel 3: expand bitsets (+keep) to float outputs --------
// Masks are exactly {0,1}, so output = (keep && bit) ? 1.0 : 0.0 — no need to
// re-read the 75.5 MB source. One thread per word -> 128 B stores.
__global__ __launch_bounds__(256) void expand_kernel(
    const uint32_t* __restrict__ bitsA, const uint32_t* __restrict__ bitsB,
    const int* __restrict__ meta, float* __restrict__ out)
{
    int w = blockIdx.x * 256 + threadIdx.x;      // global word 0..589823
    int tensor = (w >= WPT);
    int lw = tensor ? (w - WPT) : w;
    const uint32_t* bits = tensor ? bitsB : bitsA;
    const int* flags = meta + (tensor ? 48 : 32);
    int m = lw / WPM;
    bool keep = (flags[m] == 0);
    uint32_t wd = keep ? bits[lw] : 0u;
    float4* o4 = (float4*)(out + (size_t)w * 32);
#pragma unroll
    for (int q = 0; q < 8; ++q) {
        float4 v;
        v.x = ((wd >> (q * 4 + 0)) & 1u) ? 1.0f : 0.0f;
        v.y = ((wd >> (q * 4 + 1)) & 1u) ? 1.0f : 0.0f;
        v.z = ((wd >> (q * 4 + 2)) & 1u) ? 1.0f : 0.0f;
        v.w = ((wd >> (q * 4 + 3)) & 1u) ? 1.0f : 0.0f;
        o4[q] = v;
    }
    if (w < 2 * NM) {   // keep_a / keep_b tail: flagsA,flagsB contiguous
        const int* f = meta + 32;
        out[(size_t)2 * NM * HW_P + w] = f[w] ? 0.0f : 1.0f;
    }
}

extern "C" void kernel_launch(void* const* d_in, const int* in_sizes, int n_in,
                              void* d_out, int out_size, void* d_ws, size_t ws_size,
                              hipStream_t stream)
{
    const float* ma = (const float*)d_in[0];
    const float* mb = (const float*)d_in[1];
    const float* sa = (const float*)d_in[2];
    const float* sb = (const float*)d_in[3];
    float* out = (float*)d_out;
    char* ws = (char*)d_ws;

    uint32_t* bitsA = (uint32_t*)(ws);                 // 1,179,648 B
    uint32_t* bitsB = (uint32_t*)(ws + 1179648);       // 1,179,648 B
    int* meta       = (int*)(ws + 2359296);            // 384 B used, 512 pad
    uint4* msg      = (uint4*)(ws + 2359808);          // 30 slots * 73,792 B

    hipMemsetAsync(meta, 0, 512, stream);              // pc/flags/prod/cons = 0

    binarize_kernel<<<2304, 256, 0, stream>>>(ma, mb, bitsA, bitsB, meta);
    pipeline_kernel<<<NM, PT, 0, stream>>>(sa, sb, bitsA, bitsB, meta, msg);
    expand_kernel<<<2304, 256, 0, stream>>>(bitsA, bitsB, meta, out);
}

// Round 3
// 306.027 us; speedup vs baseline: 2.2227x; 1.1441x over previous
//
#include <hip/hip_runtime.h>
#include <stdint.h>

#define NM 16
#define HW_P 589824            // 768*768 pixels per mask
#define WPM 18432              // 32-bit words per mask
#define CPM 4608               // uint4 chunks per mask
#define F4PM 147456            // float4s per mask
#define F4PT 2359296           // float4s per tensor (16 masks)
#define PT 512                 // pipeline threads
#define NG 8                   // column groups (WGs), 2 cols each
#define NT 8                   // row tiles (2 rows each)
#define SLOT_U4 9220           // uint4 per slot: 2*4608 data + 1 meta + pad

// meta ints: [32..47] flagsA | [48..63] flagsB | [64..71] prod | [80..87] cons

// spread 8 bits to every 4th bit of a 32-bit word
__device__ __forceinline__ uint32_t spread4(uint32_t x) {
    uint32_t t = (x | (x << 12)) & 0x000F000Fu;
    t = (t | (t << 6)) & 0x03030303u;
    t = (t | (t << 3)) & 0x11111111u;
    return t;
}

// ---------------- kernel 1: binarize (coalesced, ballot-packed) ------------
// One float4 per thread (lane-consecutive). A wave covers 64 float4 = 256
// pixels = 8 words; lanes 0..7 write the packed words.
__global__ __launch_bounds__(256) void binarize_kernel(
    const float* __restrict__ ma, const float* __restrict__ mb,
    uint32_t* __restrict__ bitsA, uint32_t* __restrict__ bitsB)
{
    int g = blockIdx.x * 256 + threadIdx.x;        // float4 index
    int tensor = (g >= F4PT);                      // boundary %64==0: wave-uniform
    int lg = tensor ? (g - F4PT) : g;
    const float* src = tensor ? mb : ma;
    float4 v = ((const float4*)src)[lg];
    unsigned long long q0 = __ballot(v.x > 0.0f);
    unsigned long long q1 = __ballot(v.y > 0.0f);
    unsigned long long q2 = __ballot(v.z > 0.0f);
    unsigned long long q3 = __ballot(v.w > 0.0f);
    int lane = threadIdx.x & 63;
    if (lane < 8) {
        uint32_t wd = spread4((uint32_t)(q0 >> (8 * lane)) & 0xFFu)
                    | (spread4((uint32_t)(q1 >> (8 * lane)) & 0xFFu) << 1)
                    | (spread4((uint32_t)(q2 >> (8 * lane)) & 0xFFu) << 2)
                    | (spread4((uint32_t)(q3 >> (8 * lane)) & 0xFFu) << 3);
        uint32_t* bits = tensor ? bitsB : bitsA;
        bits[((lg & ~63) >> 3) + lane] = wd;       // word = 8 float4s
    }
}

// ---------------- kernel 2: tiled systolic wavefront -----------------------
// 8 WGs; WG g owns columns 2g,2g+1 (b in registers). Rows flow in 2-row
// tiles g-1 -> g as 144 KB messages (double-buffered, credit-reused).
// 15 release/acquire stages on the critical path (vs 31 in R2).
__global__ __launch_bounds__(PT) void pipeline_kernel(
    const float* __restrict__ sa, const float* __restrict__ sb,
    uint32_t* bitsA, uint32_t* bitsB, int* meta, uint4* msg)
{
    int* flagsA = meta + 32;
    int* flagsB = meta + 48;
    int* prod   = meta + 64;
    int* cons   = meta + 80;

    const int g = blockIdx.x;
    const int tid = threadIdx.x;
    const int wave = tid >> 6, lane = tid & 63;
    const int c0 = 2 * g, c1 = 2 * g + 1;

    __shared__ int partial[2][PT / 64];
    __shared__ int smeta[4];

    uint4* A4 = (uint4*)bitsA;
    uint4* B4 = (uint4*)bitsB;

    uint4 b0[9], b1[9], a0[9], a1[9];
    int par = 0;

    auto reduce_sum = [&](int s) -> int {
#pragma unroll
        for (int off = 32; off >= 1; off >>= 1) s += __shfl_xor(s, off);
        if (lane == 0) partial[par][wave] = s;
        __syncthreads();
        int tot = 0;
#pragma unroll
        for (int w = 0; w < PT / 64; ++w) tot += partial[par][w];
        par ^= 1;
        return tot;
    };

#pragma unroll
    for (int w = 0; w < 9; ++w) {
        b0[w] = B4[(size_t)c0 * CPM + tid + PT * w];
        b1[w] = B4[(size_t)c1 * CPM + tid + PT * w];
    }
    int s0 = 0, s1 = 0;
#pragma unroll
    for (int w = 0; w < 9; ++w) {
        s0 += __popc(b0[w].x) + __popc(b0[w].y) + __popc(b0[w].z) + __popc(b0[w].w);
        s1 += __popc(b1[w].x) + __popc(b1[w].y) + __popc(b1[w].z) + __popc(b1[w].w);
    }
    int pcb0 = reduce_sum(s0);
    int pcb1 = reduce_sum(s1);
    float sb0 = sb[c0], sb1 = sb[c1];
    int fb0 = 0, fb1 = 0;

    for (int t = 0; t < NT; ++t) {
        const int i0 = 2 * t, i1 = 2 * t + 1;
        uint4* slot_in  = (g > 0) ? (msg + (size_t)((g - 1) * 2 + (t & 1)) * SLOT_U4) : msg;
        uint4* slot_out = msg + (size_t)(g * 2 + (t & 1)) * SLOT_U4;

        if (g > 0 && tid == 0) {
            while (__hip_atomic_load(&prod[g - 1], __ATOMIC_ACQUIRE,
                                     __HIP_MEMORY_SCOPE_AGENT) < t + 1)
                __builtin_amdgcn_s_sleep(1);
            const int* mi = (const int*)(slot_in + 2 * CPM);
            smeta[0] = mi[0]; smeta[1] = mi[1]; smeta[2] = mi[2]; smeta[3] = mi[3];
        }
        if (g < NG - 1 && t >= 2 && tid == 1) {
            while (__hip_atomic_load(&cons[g], __ATOMIC_RELAXED,
                                     __HIP_MEMORY_SCOPE_AGENT) < t - 1)
                __builtin_amdgcn_s_sleep(1);
        }
        __syncthreads();   // B1: flag seen, caches inv'd, smeta visible

        int pca0, pca1, fa0, fa1;
        if (g == 0) {
#pragma unroll
            for (int w = 0; w < 9; ++w) {
                a0[w] = A4[(size_t)i0 * CPM + tid + PT * w];
                a1[w] = A4[(size_t)i1 * CPM + tid + PT * w];
            }
            int t0 = 0, t1 = 0;
#pragma unroll
            for (int w = 0; w < 9; ++w) {
                t0 += __popc(a0[w].x) + __popc(a0[w].y) + __popc(a0[w].z) + __popc(a0[w].w);
                t1 += __popc(a1[w].x) + __popc(a1[w].y) + __popc(a1[w].z) + __popc(a1[w].w);
            }
            pca0 = reduce_sum(t0);
            pca1 = reduce_sum(t1);
            fa0 = 0; fa1 = 0;
        } else {
            pca0 = smeta[0]; pca1 = smeta[1]; fa0 = smeta[2]; fa1 = smeta[3];
#pragma unroll
            for (int w = 0; w < 9; ++w) {
                a0[w] = slot_in[tid + PT * w];
                a1[w] = slot_in[CPM + tid + PT * w];
            }
            __syncthreads();   // B2: all slot loads retired (vmcnt drained)
            if (tid == 2)      // release the slot back to the producer
                __hip_atomic_store(&cons[g - 1], t + 1, __ATOMIC_RELAXED,
                                   __HIP_MEMORY_SCOPE_AGENT);
        }

        float sa0 = sa[i0], sa1 = sa[i1];

        // 4 pairs in reference-respecting order: (i0,c0) (i0,c1) (i1,c0) (i1,c1)
        auto do_pair = [&](uint4* a, int& pa, int& fa, uint4* b, int& pb, int& fb,
                           float sca, float scb) {
            int s = 0;
#pragma unroll
            for (int w = 0; w < 9; ++w) {
                s += __popc(a[w].x & b[w].x) + __popc(a[w].y & b[w].y)
                   + __popc(a[w].z & b[w].z) + __popc(a[w].w & b[w].w);
            }
            int inter = reduce_sum(s);
            int uni = pa + pb - inter;
            // replicate reference fp32 arithmetic exactly
            float iou = (float)inter / fmaxf((float)uni, 1.0f);
            bool a_wins = sca > scb;
            if (iou > 0.8f) {
                if (a_wins) fb = 1; else fa = 1;
            } else if (inter > 0) {
                if (a_wins) {
                    pb -= inter;
#pragma unroll
                    for (int w = 0; w < 9; ++w) {
                        b[w].x &= ~a[w].x; b[w].y &= ~a[w].y;
                        b[w].z &= ~a[w].z; b[w].w &= ~a[w].w;
                    }
                } else {
                    pa -= inter;
#pragma unroll
                    for (int w = 0; w < 9; ++w) {
                        a[w].x &= ~b[w].x; a[w].y &= ~b[w].y;
                        a[w].z &= ~b[w].z; a[w].w &= ~b[w].w;
                    }
                }
            }
        };
        do_pair(a0, pca0, fa0, b0, pcb0, fb0, sa0, sb0);
        do_pair(a0, pca0, fa0, b1, pcb1, fb1, sa0, sb1);
        do_pair(a1, pca1, fa1, b0, pcb0, fb0, sa1, sb0);
        do_pair(a1, pca1, fa1, b1, pcb1, fb1, sa1, sb1);

        if (g < NG - 1) {
#pragma unroll
            for (int w = 0; w < 9; ++w) {
                slot_out[tid + PT * w] = a0[w];
                slot_out[CPM + tid + PT * w] = a1[w];
            }
            __syncthreads();   // B3: data stores drained into L2
            if (tid == 0) {
                int* mo = (int*)(slot_out + 2 * CPM);
                mo[0] = pca0; mo[1] = pca1; mo[2] = fa0; mo[3] = fa1;
                // RELEASE: vmcnt drain + buffer_wbl2 covers data + meta, then flag
                __hip_atomic_store(&prod[g], t + 1, __ATOMIC_RELEASE,
                                   __HIP_MEMORY_SCOPE_AGENT);
            }
        } else {
            // last group: rows are final; overwrite bitsA in place
#pragma unroll
            for (int w = 0; w < 9; ++w) {
                A4[(size_t)i0 * CPM + tid + PT * w] = a0[w];
                A4[(size_t)i1 * CPM + tid + PT * w] = a1[w];
            }
            if (tid == 0) { flagsA[i0] = fa0; flagsA[i1] = fa1; }
        }
    }
    // final b columns + flags; kernel-end writeback publishes to expand_kernel
#pragma unroll
    for (int w = 0; w < 9; ++w) {
        B4[(size_t)c0 * CPM + tid + PT * w] = b0[w];
        B4[(size_t)c1 * CPM + tid + PT * w] = b1[w];
    }
    if (tid == 0) { flagsB[c0] = fb0; flagsB[c1] = fb1; }
}

// ---------------- kernel 3: expand (coalesced) -----------------------------
// One float4 per thread; 8 threads share one bitset word (L1 broadcast).
__global__ __launch_bounds__(256) void expand_kernel(
    const uint32_t* __restrict__ bitsA, const uint32_t* __restrict__ bitsB,
    const int* __restrict__ meta, float* __restrict__ out)
{
    int g = blockIdx.x * 256 + threadIdx.x;        // float4 index
    int tensor = (g >= F4PT);
    int lg = tensor ? (g - F4PT) : g;
    const uint32_t* bits = tensor ? bitsB : bitsA;
    const int* flags = meta + (tensor ? 48 : 32);
    int m = lg / F4PM;
    bool keep = (flags[m] == 0);
    uint32_t wd = keep ? bits[lg >> 3] : 0u;
    int sh = (lg & 7) * 4;
    float4 o;
    o.x = ((wd >> (sh + 0)) & 1u) ? 1.0f : 0.0f;
    o.y = ((wd >> (sh + 1)) & 1u) ? 1.0f : 0.0f;
    o.z = ((wd >> (sh + 2)) & 1u) ? 1.0f : 0.0f;
    o.w = ((wd >> (sh + 3)) & 1u) ? 1.0f : 0.0f;
    ((float4*)out)[g] = o;
    if (g < 2 * NM) {   // keep_a / keep_b tail (flagsA,flagsB contiguous)
        const int* f = meta + 32;
        out[(size_t)2 * NM * HW_P + g] = f[g] ? 0.0f : 1.0f;
    }
}

extern "C" void kernel_launch(void* const* d_in, const int* in_sizes, int n_in,
                              void* d_out, int out_size, void* d_ws, size_t ws_size,
                              hipStream_t stream)
{
    const float* ma = (const float*)d_in[0];
    const float* mb = (const float*)d_in[1];
    const float* sa = (const float*)d_in[2];
    const float* sb = (const float*)d_in[3];
    float* out = (float*)d_out;
    char* ws = (char*)d_ws;

    uint32_t* bitsA = (uint32_t*)(ws);             // 1,179,648 B
    uint32_t* bitsB = (uint32_t*)(ws + 1179648);   // 1,179,648 B
    int* meta       = (int*)(ws + 2359296);        // 512 B reserved
    uint4* msg      = (uint4*)(ws + 2359808);      // 14 slots * 147,520 B

    // only prod/cons need zeroing (flags are written unconditionally,
    // popcounts are computed inside pipeline_kernel)
    hipMemsetAsync(meta + 64, 0, 128, stream);

    binarize_kernel<<<18432, 256, 0, stream>>>(ma, mb, bitsA, bitsB);
    pipeline_kernel<<<NG, PT, 0, stream>>>(sa, sb, bitsA, bitsB, meta, msg);
    expand_kernel<<<18432, 256, 0, stream>>>(bitsA, bitsB, meta, out);
}

// Round 4
// 252.098 us; speedup vs baseline: 2.6982x; 1.2139x over previous
//
#include <hip/hip_runtime.h>
#include <stdint.h>

#define NM 16
#define HW_P 589824            // 768*768 pixels per mask
#define WPM 18432              // 32-bit words per mask
#define U8PM 9216              // 64-bit words per mask
#define F4PM 147456            // float4s per mask
#define F4PT 2359296           // float4s per tensor (16 masks)
#define PT 512                 // pipeline threads
#define NG 8                   // column groups (WGs), 2 cols each
#define U8PT 18                // u64 per thread per mask (9216/512)

typedef unsigned long long u64;

// meta ints: [32..47] flagsA | [48..63] flagsB | [64..71] cons (boundary g)
// [96..207] prodflag[(g)*16 + t], one-shot: bit0 valid | bits1..20 pca | bit21 fa

// spread 8 bits to every 4th bit of a 32-bit word
__device__ __forceinline__ uint32_t spread4(uint32_t x) {
    uint32_t t = (x | (x << 12)) & 0x000F000Fu;
    t = (t | (t << 6)) & 0x03030303u;
    t = (t | (t << 3)) & 0x11111111u;
    return t;
}

// ---------------- kernel 1: binarize (coalesced, ballot-packed) ------------
__global__ __launch_bounds__(256) void binarize_kernel(
    const float* __restrict__ ma, const float* __restrict__ mb,
    uint32_t* __restrict__ bitsA, uint32_t* __restrict__ bitsB)
{
    int g = blockIdx.x * 256 + threadIdx.x;        // float4 index
    int tensor = (g >= F4PT);                      // boundary %64==0: wave-uniform
    int lg = tensor ? (g - F4PT) : g;
    const float* src = tensor ? mb : ma;
    float4 v = ((const float4*)src)[lg];
    unsigned long long q0 = __ballot(v.x > 0.0f);
    unsigned long long q1 = __ballot(v.y > 0.0f);
    unsigned long long q2 = __ballot(v.z > 0.0f);
    unsigned long long q3 = __ballot(v.w > 0.0f);
    int lane = threadIdx.x & 63;
    if (lane < 8) {
        uint32_t wd = spread4((uint32_t)(q0 >> (8 * lane)) & 0xFFu)
                    | (spread4((uint32_t)(q1 >> (8 * lane)) & 0xFFu) << 1)
                    | (spread4((uint32_t)(q2 >> (8 * lane)) & 0xFFu) << 2)
                    | (spread4((uint32_t)(q3 >> (8 * lane)) & 0xFFu) << 3);
        uint32_t* bits = tensor ? bitsB : bitsA;
        bits[((lg & ~63) >> 3) + lane] = wd;       // word = 8 float4s
    }
}

// ---------------- kernel 2: systolic pipeline, L3-coherent messaging -------
// 8 WGs; WG g owns columns 2g,2g+1 in registers. Row a_i flows g-1 -> g as a
// 72 KB message moved entirely with relaxed AGENT-scope (sc1) 8-B atomics:
// data is coherent at L3 per-access, so no buffer_wbl2/buffer_inv per stage.
// Flag is a one-shot packed word per (boundary,tile) carrying pca+fa.
// Within a stage both pairs (i,c0),(i,c1) use ONE fused reduction:
// I0, I1, T=popc(a&b0&b1); if pair0 shrinks a, pair1's inter = I1 - T exactly.
__global__ __launch_bounds__(PT, 2) void pipeline_kernel(
    const float* __restrict__ sa, const float* __restrict__ sb,
    uint32_t* bitsA, uint32_t* bitsB, int* meta, u64* msg)
{
    int* flagsA = meta + 32;
    int* flagsB = meta + 48;
    unsigned* cons = (unsigned*)(meta + 64);
    unsigned* prodflag = (unsigned*)(meta + 96);

    const int g = blockIdx.x;
    const int tid = threadIdx.x;
    const int wave = tid >> 6, lane = tid & 63;
    const int c0 = 2 * g, c1 = 2 * g + 1;

    __shared__ int part[2][8][4];
    __shared__ unsigned smeta_s;

    u64* A8 = (u64*)bitsA;
    u64* B8 = (u64*)bitsB;

    u64 a[U8PT], b0[U8PT], b1[U8PT];
    int par = 0;

    // ---- load b columns (plain: kernel boundary made binarize visible) ----
    int v0 = 0, v1 = 0;
#pragma unroll
    for (int w = 0; w < U8PT; ++w) {
        b0[w] = B8[(size_t)c0 * U8PM + tid + PT * w];
        b1[w] = B8[(size_t)c1 * U8PM + tid + PT * w];
        v0 += __popcll(b0[w]);
        v1 += __popcll(b1[w]);
    }
#pragma unroll
    for (int off = 32; off >= 1; off >>= 1) {
        v0 += __shfl_xor(v0, off); v1 += __shfl_xor(v1, off);
    }
    if (lane == 0) { part[par][wave][0] = v0; part[par][wave][1] = v1; }
    __syncthreads();
    int pcb0 = 0, pcb1 = 0;
#pragma unroll
    for (int w = 0; w < 8; ++w) { pcb0 += part[par][w][0]; pcb1 += part[par][w][1]; }
    par ^= 1;
    float sb0 = sb[c0], sb1 = sb[c1];
    int fb0 = 0, fb1 = 0;

    for (int t = 0; t < NM; ++t) {
        if (g > 0 && tid == 0) {            // wait for row t from group g-1
            unsigned v;
            while (!(v = __hip_atomic_load(&prodflag[(g - 1) * 16 + t],
                                           __ATOMIC_RELAXED, __HIP_MEMORY_SCOPE_AGENT)))
                __builtin_amdgcn_s_sleep(1);
            smeta_s = v;
        }
        if (g < NG - 1 && t >= 2 && tid == 64) {   // slot credit (double buffer)
            while (__hip_atomic_load(&cons[g], __ATOMIC_RELAXED,
                                     __HIP_MEMORY_SCOPE_AGENT) < (unsigned)(t - 1))
                __builtin_amdgcn_s_sleep(1);
        }
        __syncthreads();   // B1: flag/credit seen, smeta visible

        int pca, fa;
        if (g == 0) {
#pragma unroll
            for (int w = 0; w < U8PT; ++w)
                a[w] = A8[(size_t)t * U8PM + tid + PT * w];
            fa = 0; pca = 0;
        } else {
            unsigned v = smeta_s;
            pca = (int)((v >> 1) & 0xFFFFFu);
            fa  = (int)((v >> 21) & 1u);
            const u64* slot_in = msg + (size_t)((g - 1) * 2 + (t & 1)) * U8PM;
#pragma unroll
            for (int w = 0; w < U8PT; ++w)
                a[w] = __hip_atomic_load(&slot_in[tid + PT * w],
                                         __ATOMIC_RELAXED, __HIP_MEMORY_SCOPE_AGENT);
        }

        int i0 = 0, i1 = 0, it = 0, ip = 0;
#pragma unroll
        for (int w = 0; w < U8PT; ++w) {
            u64 ab0 = a[w] & b0[w];
            i0 += __popcll(ab0);
            i1 += __popcll(a[w] & b1[w]);
            it += __popcll(ab0 & b1[w]);
        }
        if (g == 0) {
#pragma unroll
            for (int w = 0; w < U8PT; ++w) ip += __popcll(a[w]);
        }
#pragma unroll
        for (int off = 32; off >= 1; off >>= 1) {
            i0 += __shfl_xor(i0, off); i1 += __shfl_xor(i1, off);
            it += __shfl_xor(it, off); ip += __shfl_xor(ip, off);
        }
        if (lane == 0) {
            part[par][wave][0] = i0; part[par][wave][1] = i1;
            part[par][wave][2] = it; part[par][wave][3] = ip;
        }
        __syncthreads();   // B2: partials visible, all message loads retired
        if (g > 0 && tid == 65)   // release slot back to producer
            __hip_atomic_store(&cons[g - 1], (unsigned)(t + 1),
                               __ATOMIC_RELAXED, __HIP_MEMORY_SCOPE_AGENT);
        int I0 = 0, I1 = 0, T = 0, PC = 0;
#pragma unroll
        for (int w = 0; w < 8; ++w) {
            I0 += part[par][w][0]; I1 += part[par][w][1];
            T  += part[par][w][2]; PC += part[par][w][3];
        }
        par ^= 1;
        if (g == 0) pca = PC;

        float sai = sa[t];
        // ---- pair (t, c0): replicate reference fp32 arithmetic exactly ----
        bool aupd = false;
        {
            int inter = I0;
            int uni = pca + pcb0 - inter;
            float iou = (float)inter / fmaxf((float)uni, 1.0f);
            bool aw = sai > sb0;
            if (iou > 0.8f) { if (aw) fb0 = 1; else fa = 1; }
            else if (inter > 0) {
                if (aw) {
                    pcb0 -= inter;
#pragma unroll
                    for (int w = 0; w < U8PT; ++w) b0[w] &= ~a[w];
                } else {
                    pca -= inter; aupd = true;
#pragma unroll
                    for (int w = 0; w < U8PT; ++w) a[w] &= ~b0[w];
                }
            }
        }
        // ---- pair (t, c1): exact inter via speculative triple term --------
        {
            int inter = aupd ? (I1 - T) : I1;
            int uni = pca + pcb1 - inter;
            float iou = (float)inter / fmaxf((float)uni, 1.0f);
            bool aw = sai > sb1;
            if (iou > 0.8f) { if (aw) fb1 = 1; else fa = 1; }
            else if (inter > 0) {
                if (aw) {
                    pcb1 -= inter;
#pragma unroll
                    for (int w = 0; w < U8PT; ++w) b1[w] &= ~a[w];
                } else {
                    pca -= inter;
#pragma unroll
                    for (int w = 0; w < U8PT; ++w) a[w] &= ~b1[w];
                }
            }
        }

        if (g < NG - 1) {
            u64* slot_out = msg + (size_t)(g * 2 + (t & 1)) * U8PM;
#pragma unroll
            for (int w = 0; w < U8PT; ++w)
                __hip_atomic_store(&slot_out[tid + PT * w], a[w],
                                   __ATOMIC_RELAXED, __HIP_MEMORY_SCOPE_AGENT);
            __syncthreads();   // B3: vmcnt(0) drain -> data performed at L3
            if (tid == 0)
                __hip_atomic_store(&prodflag[g * 16 + t],
                                   1u | ((unsigned)pca << 1) | ((unsigned)fa << 21),
                                   __ATOMIC_RELAXED, __HIP_MEMORY_SCOPE_AGENT);
        } else {
            // last group: row final; plain store, kernel-end flush publishes
#pragma unroll
            for (int w = 0; w < U8PT; ++w)
                A8[(size_t)t * U8PM + tid + PT * w] = a[w];
            if (tid == 0) flagsA[t] = fa;
        }
    }
    // final b columns + flags
#pragma unroll
    for (int w = 0; w < U8PT; ++w) {
        B8[(size_t)c0 * U8PM + tid + PT * w] = b0[w];
        B8[(size_t)c1 * U8PM + tid + PT * w] = b1[w];
    }
    if (tid == 0) { flagsB[c0] = fb0; flagsB[c1] = fb1; }
}

// ---------------- kernel 3: expand (coalesced) -----------------------------
__global__ __launch_bounds__(256) void expand_kernel(
    const uint32_t* __restrict__ bitsA, const uint32_t* __restrict__ bitsB,
    const int* __restrict__ meta, float* __restrict__ out)
{
    int g = blockIdx.x * 256 + threadIdx.x;        // float4 index
    int tensor = (g >= F4PT);
    int lg = tensor ? (g - F4PT) : g;
    const uint32_t* bits = tensor ? bitsB : bitsA;
    const int* flags = meta + (tensor ? 48 : 32);
    int m = lg / F4PM;
    bool keep = (flags[m] == 0);
    uint32_t wd = keep ? bits[lg >> 3] : 0u;
    int sh = (lg & 7) * 4;
    float4 o;
    o.x = ((wd >> (sh + 0)) & 1u) ? 1.0f : 0.0f;
    o.y = ((wd >> (sh + 1)) & 1u) ? 1.0f : 0.0f;
    o.z = ((wd >> (sh + 2)) & 1u) ? 1.0f : 0.0f;
    o.w = ((wd >> (sh + 3)) & 1u) ? 1.0f : 0.0f;
    ((float4*)out)[g] = o;
    if (g < 2 * NM) {   // keep_a / keep_b tail (flagsA,flagsB contiguous)
        const int* f = meta + 32;
        out[(size_t)2 * NM * HW_P + g] = f[g] ? 0.0f : 1.0f;
    }
}

extern "C" void kernel_launch(void* const* d_in, const int* in_sizes, int n_in,
                              void* d_out, int out_size, void* d_ws, size_t ws_size,
                              hipStream_t stream)
{
    const float* ma = (const float*)d_in[0];
    const float* mb = (const float*)d_in[1];
    const float* sa = (const float*)d_in[2];
    const float* sb = (const float*)d_in[3];
    float* out = (float*)d_out;
    char* ws = (char*)d_ws;

    uint32_t* bitsA = (uint32_t*)(ws);             // 1,179,648 B
    uint32_t* bitsB = (uint32_t*)(ws + 1179648);   // 1,179,648 B
    int* meta       = (int*)(ws + 2359296);        // 1024 B reserved
    u64* msg        = (u64*)(ws + 2360320);        // 14 slots * 73,728 B

    // zero cons[8] + prodflag[112] (one-shot flags); rest written before read
    hipMemsetAsync(meta + 64, 0, 576, stream);

    binarize_kernel<<<18432, 256, 0, stream>>>(ma, mb, bitsA, bitsB);
    pipeline_kernel<<<NG, PT, 0, stream>>>(sa, sb, bitsA, bitsB, meta, msg);
    expand_kernel<<<18432, 256, 0, stream>>>(bitsA, bitsB, meta, out);
}